// Round 4
// baseline (252.362 us; speedup 1.0000x reference)
//
#include <hip/hip_runtime.h>

// N=512, D=512 fp32. Single fused kernel, 256 blocks x 256 threads, grid spin-barriers.
// pre_i[i,h] = sum_d he[i,d]*W0[h,d]; pre_j[j,h] = sum_d he[j,d]*W0[h,512+d]
// p[i,j] = sum_h relu(pre_i + pre_j + b0[h]) * w1[h]   (W1_b softmax-invariant)
// out = softmax_rows(p) @ h_e
//
// ws: bar[256B pad to 1024] | Cpart[8][512][1024] | Cfull[512][1024] |
//     Ppart[8][512][512] | Aw[512][512] | Opart[8][512][512]

typedef float v2f __attribute__((ext_vector_type(2)));

#define NBLK 256
#define AS_STR 132   // 128 + 4 pad (16B-aligned rows: 132*4=528=16*33)
#define BS_STR 68    // 64 + 4 pad  (68*4=272=16*17)

__device__ __forceinline__ void gbar(int* bar, int phase) {
    __syncthreads();
    if (threadIdx.x == 0) {
        __threadfence();  // agent-scope release of all prior writes
        __hip_atomic_fetch_add(&bar[phase], 1, __ATOMIC_RELEASE, __HIP_MEMORY_SCOPE_AGENT);
        while (__hip_atomic_load(&bar[phase], __ATOMIC_ACQUIRE, __HIP_MEMORY_SCOPE_AGENT) < NBLK) {
            __builtin_amdgcn_s_sleep(2);
        }
    }
    __syncthreads();
}

__global__ __launch_bounds__(256) void fused(const float* __restrict__ he,
                                             const float* __restrict__ w0,
                                             const float* __restrict__ b0,
                                             const float* __restrict__ w1,
                                             int* __restrict__ bar,
                                             float* __restrict__ Cpart,
                                             float* __restrict__ Cfull,
                                             float* __restrict__ Ppart,
                                             float* __restrict__ Aw,
                                             float* __restrict__ Opart,
                                             float* __restrict__ outp) {
    __shared__ float smem[12864];  // 51456 B
    const int tid = threadIdx.x;
    const int bid = blockIdx.x;
    const int tx = tid & 15, ty = tid >> 4;

    // ---------------- Phase A: C-partials, NT GEMM, 128x128 tile, 8x8 micro, K-split 8
    {
        const int ks = bid & 7, bi = (bid >> 3) & 3, bc = bid >> 5;
        const int c0 = bc * 128, i0 = bi * 128, kb0 = ks * 64;
        const int hrow0 = c0 & 511;
        const int dofs = (c0 >= 512) ? 512 : 0;
        float* As = smem;           // [d(32)][i(128)] stride AS_STR
        float* Bs = smem + 4224;    // [d(32)][c(128)] stride AS_STR
        v2f acc[8][4] = {};
        for (int kt = 0; kt < 2; ++kt) {
            const int kb = kb0 + kt * 32;
            #pragma unroll
            for (int r = 0; r < 4; ++r) {
                int f = tid + r * 256, row = f >> 3, kc = (f & 7) * 4;
                float4 a = *(const float4*)&he[(i0 + row) * 512 + kb + kc];
                As[(kc + 0) * AS_STR + row] = a.x;
                As[(kc + 1) * AS_STR + row] = a.y;
                As[(kc + 2) * AS_STR + row] = a.z;
                As[(kc + 3) * AS_STR + row] = a.w;
            }
            #pragma unroll
            for (int r = 0; r < 4; ++r) {
                int f = tid + r * 256, row = f >> 3, kc = (f & 7) * 4;
                float4 b = *(const float4*)&w0[(hrow0 + row) * 1024 + dofs + kb + kc];
                Bs[(kc + 0) * AS_STR + row] = b.x;
                Bs[(kc + 1) * AS_STR + row] = b.y;
                Bs[(kc + 2) * AS_STR + row] = b.z;
                Bs[(kc + 3) * AS_STR + row] = b.w;
            }
            __syncthreads();
            #pragma unroll
            for (int k = 0; k < 32; ++k) {
                float4 a0 = *(const float4*)&As[k * AS_STR + 4 * ty];
                float4 a1 = *(const float4*)&As[k * AS_STR + 64 + 4 * ty];
                float4 q0 = *(const float4*)&Bs[k * AS_STR + 4 * tx];
                float4 q1 = *(const float4*)&Bs[k * AS_STR + 64 + 4 * tx];
                v2f bb[4] = {{q0.x, q0.y}, {q0.z, q0.w}, {q1.x, q1.y}, {q1.z, q1.w}};
                float av[8] = {a0.x, a0.y, a0.z, a0.w, a1.x, a1.y, a1.z, a1.w};
                #pragma unroll
                for (int ii = 0; ii < 8; ++ii) {
                    v2f av2 = {av[ii], av[ii]};
                    #pragma unroll
                    for (int jj = 0; jj < 4; ++jj)
                        acc[ii][jj] = __builtin_elementwise_fma(av2, bb[jj], acc[ii][jj]);
                }
            }
            __syncthreads();
        }
        float* op = Cpart + (size_t)ks * 512 * 1024;
        #pragma unroll
        for (int ii = 0; ii < 8; ++ii) {
            int row = i0 + ((ii < 4) ? (4 * ty + ii) : (64 + 4 * ty + ii - 4));
            float4 v0 = make_float4(acc[ii][0].x, acc[ii][0].y, acc[ii][1].x, acc[ii][1].y);
            float4 v1 = make_float4(acc[ii][2].x, acc[ii][2].y, acc[ii][3].x, acc[ii][3].y);
            *(float4*)&op[row * 1024 + c0 + 4 * tx] = v0;
            *(float4*)&op[row * 1024 + c0 + 64 + 4 * tx] = v1;
        }
    }
    gbar(bar, 0);

    // ---------------- Phase A': Cfull = sum of 8 partials, + b0 folded into j-half
    {
        const int g = bid * 256 + tid;   // 0..65535
        const int base = g * 8;
        const int col = base & 1023;
        float4 s0 = make_float4(0, 0, 0, 0), s1 = make_float4(0, 0, 0, 0);
        #pragma unroll
        for (int s = 0; s < 8; ++s) {
            float4 a = *(const float4*)&Cpart[s * 524288 + base];
            float4 b = *(const float4*)&Cpart[s * 524288 + base + 4];
            s0.x += a.x; s0.y += a.y; s0.z += a.z; s0.w += a.w;
            s1.x += b.x; s1.y += b.y; s1.z += b.z; s1.w += b.w;
        }
        if (col >= 512) {
            float4 a = *(const float4*)&b0[col - 512];
            float4 b = *(const float4*)&b0[col - 512 + 4];
            s0.x += a.x; s0.y += a.y; s0.z += a.z; s0.w += a.w;
            s1.x += b.x; s1.y += b.y; s1.z += b.z; s1.w += b.w;
        }
        *(float4*)&Cfull[base] = s0;
        *(float4*)&Cfull[base + 4] = s1;
    }
    gbar(bar, 1);

    // ---------------- Phase B: score partials, 128i x 64j tile, 8x4 micro, h-slice 64
    {
        const int hs = bid & 7, bi = (bid >> 3) & 3, bj = bid >> 5;
        const int j0 = bj * 64, i0 = bi * 128, hb = hs * 64;
        float* As = smem;            // [h(64)][i(128)]
        float* Bs = smem + 8448;     // [h(64)][j(64)]
        float* Ws = smem + 12800;
        #pragma unroll
        for (int r = 0; r < 8; ++r) {
            int f = tid + r * 256, row = f >> 4, hc = (f & 15) * 4;
            float4 a = *(const float4*)&Cfull[(i0 + row) * 1024 + hb + hc];
            As[(hc + 0) * AS_STR + row] = a.x;
            As[(hc + 1) * AS_STR + row] = a.y;
            As[(hc + 2) * AS_STR + row] = a.z;
            As[(hc + 3) * AS_STR + row] = a.w;
        }
        #pragma unroll
        for (int r = 0; r < 4; ++r) {
            int f = tid + r * 256, row = f >> 4, hc = (f & 15) * 4;
            float4 a = *(const float4*)&Cfull[(j0 + row) * 1024 + 512 + hb + hc];
            Bs[(hc + 0) * BS_STR + row] = a.x;
            Bs[(hc + 1) * BS_STR + row] = a.y;
            Bs[(hc + 2) * BS_STR + row] = a.z;
            Bs[(hc + 3) * BS_STR + row] = a.w;
        }
        if (tid < 64) Ws[tid] = w1[hb + tid];
        __syncthreads();
        v2f acc[8][2] = {};
        const v2f z2 = {0.0f, 0.0f};
        #pragma unroll 16
        for (int k = 0; k < 64; ++k) {
            float4 a0 = *(const float4*)&As[k * AS_STR + 4 * ty];
            float4 a1 = *(const float4*)&As[k * AS_STR + 64 + 4 * ty];
            float4 b = *(const float4*)&Bs[k * BS_STR + 4 * tx];
            float w = Ws[k];
            v2f w2 = {w, w};
            v2f b01 = {b.x, b.y}, b23 = {b.z, b.w};
            float av[8] = {a0.x, a0.y, a0.z, a0.w, a1.x, a1.y, a1.z, a1.w};
            #pragma unroll
            for (int ii = 0; ii < 8; ++ii) {
                v2f av2 = {av[ii], av[ii]};
                v2f x0 = av2 + b01;
                v2f x1 = av2 + b23;
                x0 = __builtin_elementwise_max(x0, z2);
                x1 = __builtin_elementwise_max(x1, z2);
                acc[ii][0] = __builtin_elementwise_fma(x0, w2, acc[ii][0]);
                acc[ii][1] = __builtin_elementwise_fma(x1, w2, acc[ii][1]);
            }
        }
        float* op = Ppart + (size_t)hs * 262144;
        #pragma unroll
        for (int ii = 0; ii < 8; ++ii) {
            int row = i0 + ((ii < 4) ? (4 * ty + ii) : (64 + 4 * ty + ii - 4));
            float4 v = make_float4(acc[ii][0].x, acc[ii][0].y, acc[ii][1].x, acc[ii][1].y);
            *(float4*)&op[row * 512 + j0 + 4 * tx] = v;
        }
    }
    gbar(bar, 2);

    // ---------------- Phase C: reduce 8 P-partials + row softmax (2 rows/block)
    {
        float* red = smem;
        for (int rr = 0; rr < 2; ++rr) {
            const int i = bid * 2 + rr;
            float p0 = 0.f, p1 = 0.f;
            #pragma unroll
            for (int s = 0; s < 8; ++s) {
                p0 += Ppart[s * 262144 + i * 512 + tid];
                p1 += Ppart[s * 262144 + i * 512 + tid + 256];
            }
            red[tid] = fmaxf(p0, p1);
            __syncthreads();
            for (int s = 128; s > 0; s >>= 1) {
                if (tid < s) red[tid] = fmaxf(red[tid], red[tid + s]);
                __syncthreads();
            }
            const float m = red[0];
            __syncthreads();
            const float e0 = __expf(p0 - m);
            const float e1 = __expf(p1 - m);
            red[tid] = e0 + e1;
            __syncthreads();
            for (int s = 128; s > 0; s >>= 1) {
                if (tid < s) red[tid] += red[tid + s];
                __syncthreads();
            }
            const float inv = 1.0f / red[0];
            Aw[i * 512 + tid] = e0 * inv;
            Aw[i * 512 + tid + 256] = e1 * inv;
            __syncthreads();
        }
    }
    gbar(bar, 3);

    // ---------------- Phase D: out partials, 128i x 64d tile, 8x4 micro, K(j)-split 8
    {
        const int ks = bid & 7, bi = (bid >> 3) & 3, bd = bid >> 5;
        const int d0 = bd * 64, i0 = bi * 128, kb0 = ks * 64;
        float* As = smem;            // [k(64)][i(128)]
        float* Bs = smem + 8448;     // [k(64)][d(64)] natural
        #pragma unroll
        for (int r = 0; r < 8; ++r) {
            int f = tid + r * 256, row = f >> 4, kc = (f & 15) * 4;
            float4 a = *(const float4*)&Aw[(i0 + row) * 512 + kb0 + kc];
            As[(kc + 0) * AS_STR + row] = a.x;
            As[(kc + 1) * AS_STR + row] = a.y;
            As[(kc + 2) * AS_STR + row] = a.z;
            As[(kc + 3) * AS_STR + row] = a.w;
        }
        #pragma unroll
        for (int r = 0; r < 4; ++r) {
            int f = tid + r * 256, row = f >> 4, dc = (f & 15) * 4;
            *(float4*)&Bs[row * BS_STR + dc] = *(const float4*)&he[(kb0 + row) * 512 + d0 + dc];
        }
        __syncthreads();
        v2f acc[8][2] = {};
        #pragma unroll 16
        for (int k = 0; k < 64; ++k) {
            float4 a0 = *(const float4*)&As[k * AS_STR + 4 * ty];
            float4 a1 = *(const float4*)&As[k * AS_STR + 64 + 4 * ty];
            float4 b = *(const float4*)&Bs[k * BS_STR + 4 * tx];
            v2f b01 = {b.x, b.y}, b23 = {b.z, b.w};
            float av[8] = {a0.x, a0.y, a0.z, a0.w, a1.x, a1.y, a1.z, a1.w};
            #pragma unroll
            for (int ii = 0; ii < 8; ++ii) {
                v2f av2 = {av[ii], av[ii]};
                acc[ii][0] = __builtin_elementwise_fma(av2, b01, acc[ii][0]);
                acc[ii][1] = __builtin_elementwise_fma(av2, b23, acc[ii][1]);
            }
        }
        float* op = Opart + (size_t)ks * 262144;
        #pragma unroll
        for (int ii = 0; ii < 8; ++ii) {
            int row = i0 + ((ii < 4) ? (4 * ty + ii) : (64 + 4 * ty + ii - 4));
            float4 v = make_float4(acc[ii][0].x, acc[ii][0].y, acc[ii][1].x, acc[ii][1].y);
            *(float4*)&op[row * 512 + d0 + 4 * tx] = v;
        }
    }
    gbar(bar, 4);

    // ---------------- Phase D': reduce 8 out-partials -> d_out
    {
        const int base = (bid * 256 + tid) * 4;
        float4 s0 = make_float4(0, 0, 0, 0);
        #pragma unroll
        for (int s = 0; s < 8; ++s) {
            float4 a = *(const float4*)&Opart[s * 262144 + base];
            s0.x += a.x; s0.y += a.y; s0.z += a.z; s0.w += a.w;
        }
        *(float4*)&outp[base] = s0;
    }
}

extern "C" void kernel_launch(void* const* d_in, const int* in_sizes, int n_in,
                              void* d_out, int out_size, void* d_ws, size_t ws_size,
                              hipStream_t stream) {
    const float* he = (const float*)d_in[0];   // (512, 512)
    const float* w0 = (const float*)d_in[1];   // (512, 1024)
    const float* b0 = (const float*)d_in[2];   // (512,)
    const float* w1 = (const float*)d_in[3];   // (1, 512)
    // d_in[4] = W1_b: softmax-invariant, unused.
    int* bar = (int*)d_ws;
    float* base = (float*)((char*)d_ws + 1024);
    float* Cpart = base;                       // 8*512*1024
    float* Cfull = Cpart + 8 * 512 * 1024;     // 512*1024
    float* Ppart = Cfull + 524288;             // 8*512*512
    float* Aw    = Ppart + 8 * 262144;         // 512*512
    float* Opart = Aw + 262144;                // 8*512*512

    hipMemsetAsync(d_ws, 0, 1024, stream);     // zero barrier counters every call
    fused<<<NBLK, 256, 0, stream>>>(he, w0, b0, w1, bar, Cpart, Cfull, Ppart, Aw,
                                    Opart, (float*)d_out);
}

// Round 5
// 155.093 us; speedup vs baseline: 1.6272x; 1.6272x over previous
//
#include <hip/hip_runtime.h>

// N=512, D=512 fp32. Single fused kernel, 256 blocks x 256 threads, 3 flag-based
// grid barriers (contention-free: one RMW per block, relaxed polling on a flag).
// pre_i[i,h] = sum_d he[i,d]*W0[h,d]; pre_j[j,h] = sum_d he[j,d]*W0[h,512+d]
// p[i,j] = sum_h relu(pre_i + pre_j + b0[h]) * w1[h]   (W1_b softmax-invariant)
// out = softmax_rows(p) @ h_e
//
// ws: bar[1024B] | Cpart[2][512][1024] | Ppart[8][512][512] | Aw[512][512]

typedef float v2f __attribute__((ext_vector_type(2)));

#define NBLK 256
#define AS_STR 132   // 128 + 4 pad
#define BS_STR 68    // 64 + 4 pad

// counts at bar[0..2], flags at bar[32..34] (separate 128B line)
__device__ __forceinline__ void gbar(int* bar, int phase) {
    __syncthreads();
    if (threadIdx.x == 0) {
        int* cnt = bar + phase;
        int* flg = bar + 32 + phase;
        int prev = __hip_atomic_fetch_add(cnt, 1, __ATOMIC_ACQ_REL, __HIP_MEMORY_SCOPE_AGENT);
        if (prev == NBLK - 1) {
            __hip_atomic_store(flg, 1, __ATOMIC_RELEASE, __HIP_MEMORY_SCOPE_AGENT);
        } else {
            while (__hip_atomic_load(flg, __ATOMIC_RELAXED, __HIP_MEMORY_SCOPE_AGENT) == 0) {
                __builtin_amdgcn_s_sleep(32);
            }
            (void)__hip_atomic_load(flg, __ATOMIC_ACQUIRE, __HIP_MEMORY_SCOPE_AGENT);
        }
    }
    __syncthreads();
}

__global__ __launch_bounds__(256) void fused(const float* __restrict__ he,
                                             const float* __restrict__ w0,
                                             const float* __restrict__ b0,
                                             const float* __restrict__ w1,
                                             int* __restrict__ bar,
                                             float* __restrict__ Cpart,
                                             float* __restrict__ Ppart,
                                             float* __restrict__ Aw,
                                             float* __restrict__ outp) {
    __shared__ float smem[12864];  // 51456 B
    const int tid = threadIdx.x;
    const int bid = blockIdx.x;
    const int tx = tid & 15, ty = tid >> 4;

    // ---------------- Phase A: C-partials, NT GEMM, 64x64 tile, 4x4 micro, K-split 2
    // (proven round-3 k_pre structure)
    {
        const int ks = bid & 1, bi = (bid >> 1) & 7, bc = bid >> 4;
        const int c0 = bc * 64, i0 = bi * 64, kbase0 = ks * 256;
        const int hrow0 = c0 & 511;
        const int dofs = (c0 >= 512) ? 512 : 0;
        float* As = smem;           // [d(32)][i(64)] stride BS_STR
        float* Bs = smem + 2176;    // [d(32)][c(64)] stride BS_STR
        v2f acc[4][2] = {};
        for (int kt = 0; kt < 8; ++kt) {
            const int kb = kbase0 + kt * 32;
            #pragma unroll
            for (int r = 0; r < 2; ++r) {
                int f = tid + r * 256, row = f >> 3, kc = (f & 7) * 4;
                float4 a = *(const float4*)&he[(i0 + row) * 512 + kb + kc];
                As[(kc + 0) * BS_STR + row] = a.x;
                As[(kc + 1) * BS_STR + row] = a.y;
                As[(kc + 2) * BS_STR + row] = a.z;
                As[(kc + 3) * BS_STR + row] = a.w;
            }
            #pragma unroll
            for (int r = 0; r < 2; ++r) {
                int f = tid + r * 256, row = f >> 3, kc = (f & 7) * 4;
                float4 b = *(const float4*)&w0[(hrow0 + row) * 1024 + dofs + kb + kc];
                Bs[(kc + 0) * BS_STR + row] = b.x;
                Bs[(kc + 1) * BS_STR + row] = b.y;
                Bs[(kc + 2) * BS_STR + row] = b.z;
                Bs[(kc + 3) * BS_STR + row] = b.w;
            }
            __syncthreads();
            #pragma unroll
            for (int k = 0; k < 32; ++k) {
                float4 a = *(const float4*)&As[k * BS_STR + 4 * ty];
                float4 b = *(const float4*)&Bs[k * BS_STR + 4 * tx];
                v2f b01 = {b.x, b.y}, b23 = {b.z, b.w};
                float av[4] = {a.x, a.y, a.z, a.w};
                #pragma unroll
                for (int ii = 0; ii < 4; ++ii) {
                    v2f av2 = {av[ii], av[ii]};
                    acc[ii][0] = __builtin_elementwise_fma(av2, b01, acc[ii][0]);
                    acc[ii][1] = __builtin_elementwise_fma(av2, b23, acc[ii][1]);
                }
            }
            __syncthreads();
        }
        float* op = Cpart + (size_t)ks * 524288;
        #pragma unroll
        for (int ii = 0; ii < 4; ++ii) {
            float4 v = make_float4(acc[ii][0].x, acc[ii][0].y, acc[ii][1].x, acc[ii][1].y);
            *(float4*)&op[(i0 + 4 * ty + ii) * 1024 + c0 + 4 * tx] = v;
        }
    }
    gbar(bar, 0);

    // ---------------- Phase B: score partials, 128i x 64j tile, 8x4 micro, h-slice 64
    // (2-partial sum + bias folded into staging, proven round-3 pattern)
    {
        const int hs = bid & 7, bi = (bid >> 3) & 3, bj = bid >> 5;
        const int j0 = bj * 64, i0 = bi * 128, hb = hs * 64;
        const float* C0 = Cpart;
        const float* C1 = Cpart + 524288;
        float* As = smem;            // [h(64)][i(128)] stride AS_STR
        float* Bs = smem + 8448;     // [h(64)][j(64)]  stride BS_STR
        float* Ws = smem + 12800;
        #pragma unroll
        for (int r = 0; r < 8; ++r) {
            int f = tid + r * 256, row = f >> 4, hc = (f & 15) * 4;
            int g = (i0 + row) * 1024 + hb + hc;
            float4 a  = *(const float4*)&C0[g];
            float4 a1 = *(const float4*)&C1[g];
            As[(hc + 0) * AS_STR + row] = a.x + a1.x;
            As[(hc + 1) * AS_STR + row] = a.y + a1.y;
            As[(hc + 2) * AS_STR + row] = a.z + a1.z;
            As[(hc + 3) * AS_STR + row] = a.w + a1.w;
        }
        #pragma unroll
        for (int r = 0; r < 4; ++r) {
            int f = tid + r * 256, row = f >> 4, hc = (f & 15) * 4;
            int g = (j0 + row) * 1024 + 512 + hb + hc;
            float4 a  = *(const float4*)&C0[g];
            float4 a1 = *(const float4*)&C1[g];
            float4 bb = *(const float4*)&b0[hb + hc];
            Bs[(hc + 0) * BS_STR + row] = a.x + a1.x + bb.x;
            Bs[(hc + 1) * BS_STR + row] = a.y + a1.y + bb.y;
            Bs[(hc + 2) * BS_STR + row] = a.z + a1.z + bb.z;
            Bs[(hc + 3) * BS_STR + row] = a.w + a1.w + bb.w;
        }
        if (tid < 64) Ws[tid] = w1[hb + tid];
        __syncthreads();
        v2f acc[8][2] = {};
        const v2f z2 = {0.0f, 0.0f};
        #pragma unroll 16
        for (int k = 0; k < 64; ++k) {
            float4 a0 = *(const float4*)&As[k * AS_STR + 4 * ty];
            float4 a1 = *(const float4*)&As[k * AS_STR + 64 + 4 * ty];
            float4 b = *(const float4*)&Bs[k * BS_STR + 4 * tx];
            float w = Ws[k];
            v2f w2 = {w, w};
            v2f b01 = {b.x, b.y}, b23 = {b.z, b.w};
            float av[8] = {a0.x, a0.y, a0.z, a0.w, a1.x, a1.y, a1.z, a1.w};
            #pragma unroll
            for (int ii = 0; ii < 8; ++ii) {
                v2f av2 = {av[ii], av[ii]};
                v2f x0 = av2 + b01;
                v2f x1 = av2 + b23;
                x0 = __builtin_elementwise_max(x0, z2);
                x1 = __builtin_elementwise_max(x1, z2);
                acc[ii][0] = __builtin_elementwise_fma(x0, w2, acc[ii][0]);
                acc[ii][1] = __builtin_elementwise_fma(x1, w2, acc[ii][1]);
            }
        }
        float* op = Ppart + (size_t)hs * 262144;
        #pragma unroll
        for (int ii = 0; ii < 8; ++ii) {
            int row = i0 + ((ii < 4) ? (4 * ty + ii) : (64 + 4 * ty + ii - 4));
            float4 v = make_float4(acc[ii][0].x, acc[ii][0].y, acc[ii][1].x, acc[ii][1].y);
            *(float4*)&op[row * 512 + j0 + 4 * tx] = v;
        }
    }
    gbar(bar, 1);

    // ---------------- Phase C: reduce 8 P-partials + row softmax (2 rows/block)
    {
        float* red = smem;
        for (int rr = 0; rr < 2; ++rr) {
            const int i = bid * 2 + rr;
            float p0 = 0.f, p1 = 0.f;
            #pragma unroll
            for (int s = 0; s < 8; ++s) {
                p0 += Ppart[s * 262144 + i * 512 + tid];
                p1 += Ppart[s * 262144 + i * 512 + tid + 256];
            }
            red[tid] = fmaxf(p0, p1);
            __syncthreads();
            for (int s = 128; s > 0; s >>= 1) {
                if (tid < s) red[tid] = fmaxf(red[tid], red[tid + s]);
                __syncthreads();
            }
            const float m = red[0];
            __syncthreads();
            const float e0 = __expf(p0 - m);
            const float e1 = __expf(p1 - m);
            red[tid] = e0 + e1;
            __syncthreads();
            for (int s = 128; s > 0; s >>= 1) {
                if (tid < s) red[tid] += red[tid + s];
                __syncthreads();
            }
            const float inv = 1.0f / red[0];
            Aw[i * 512 + tid] = e0 * inv;
            Aw[i * 512 + tid + 256] = e1 * inv;
            __syncthreads();
        }
    }
    gbar(bar, 2);

    // ---------------- Phase D: out = Aw @ he, 32x32 tile, BK=32, 2x2 micro, no split
    // (proven round-2 k_out structure, writes d_out directly)
    {
        const int d0 = (bid & 15) * 32;
        const int i0 = (bid >> 4) * 32;
        float* As = smem;            // [k(32)][i(32)] stride 34
        float* Bs = smem + 1088;     // [k(32)][d(32)] stride 36
        v2f acc[2] = {};
        for (int kt = 0; kt < 16; ++kt) {
            const int kb = kt * 32;
            {
                int row = tid >> 3, kc = (tid & 7) * 4;
                float4 a = *(const float4*)&Aw[(i0 + row) * 512 + kb + kc];
                As[(kc + 0) * 34 + row] = a.x;
                As[(kc + 1) * 34 + row] = a.y;
                As[(kc + 2) * 34 + row] = a.z;
                As[(kc + 3) * 34 + row] = a.w;
            }
            {
                int row = tid >> 3, dc = (tid & 7) * 4;
                *(float4*)&Bs[row * 36 + dc] = *(const float4*)&he[(kb + row) * 512 + d0 + dc];
            }
            __syncthreads();
            #pragma unroll
            for (int k = 0; k < 32; ++k) {
                float2 a = *(const float2*)&As[k * 34 + 2 * ty];
                float2 b = *(const float2*)&Bs[k * 36 + 2 * tx];
                v2f b2 = {b.x, b.y};
                v2f a0 = {a.x, a.x}, a1 = {a.y, a.y};
                acc[0] = __builtin_elementwise_fma(a0, b2, acc[0]);
                acc[1] = __builtin_elementwise_fma(a1, b2, acc[1]);
            }
            __syncthreads();
        }
        #pragma unroll
        for (int ii = 0; ii < 2; ++ii) {
            float2 v = make_float2(acc[ii].x, acc[ii].y);
            *(float2*)&outp[(i0 + 2 * ty + ii) * 512 + d0 + 2 * tx] = v;
        }
    }
}

extern "C" void kernel_launch(void* const* d_in, const int* in_sizes, int n_in,
                              void* d_out, int out_size, void* d_ws, size_t ws_size,
                              hipStream_t stream) {
    const float* he = (const float*)d_in[0];   // (512, 512)
    const float* w0 = (const float*)d_in[1];   // (512, 1024)
    const float* b0 = (const float*)d_in[2];   // (512,)
    const float* w1 = (const float*)d_in[3];   // (1, 512)
    // d_in[4] = W1_b: softmax-invariant, unused.
    int* bar = (int*)d_ws;
    float* base = (float*)((char*)d_ws + 1024);
    float* Cpart = base;                       // 2*512*1024
    float* Ppart = Cpart + 2 * 524288;         // 8*512*512
    float* Aw    = Ppart + 8 * 262144;         // 512*512

    hipMemsetAsync(d_ws, 0, 1024, stream);     // zero barrier counters/flags every call
    fused<<<NBLK, 256, 0, stream>>>(he, w0, b0, w1, bar, Cpart, Ppart, Aw,
                                    (float*)d_out);
}

// Round 6
// 151.364 us; speedup vs baseline: 1.6673x; 1.0246x over previous
//
#include <hip/hip_runtime.h>

// N=512, D=512 fp32. Single fused kernel, 256 blocks x 256 threads.
// 3 RMW-free grid barriers: per-block arrival flag words (no same-line RMW
// serialization), block-0 relay, release/acquire chain for visibility.
// pre_i[i,h] = sum_d he[i,d]*W0[h,d]; pre_j[j,h] = sum_d he[j,d]*W0[h,512+d]
// p[i,j] = sum_h relu(pre_i + pre_j + b0[h]) * w1[h]   (W1_b softmax-invariant)
// out = softmax_rows(p) @ h_e
//
// ws: arrive[3][256] int | go[3] int | (pad to 4096B) |
//     Cpart[8][512][1024] | Ppart[8][512][512] | Aw[512][512]

typedef float v2f __attribute__((ext_vector_type(2)));

#define NBLK 256
#define AS_STR 132   // 128 + 4 pad
#define BS_STR 68    // 64 + 4 pad

__device__ __forceinline__ void gbar(int* arrive, int* go, int phase) {
    __syncthreads();
    int* arr = arrive + phase * NBLK;
    if (threadIdx.x == 0)
        __hip_atomic_store(&arr[blockIdx.x], 1, __ATOMIC_RELEASE, __HIP_MEMORY_SCOPE_AGENT);
    if (blockIdx.x == 0) {
        // 256 threads each watch one block's arrival word (no contention)
        while (__hip_atomic_load(&arr[threadIdx.x], __ATOMIC_RELAXED, __HIP_MEMORY_SCOPE_AGENT) == 0)
            __builtin_amdgcn_s_sleep(1);
        (void)__hip_atomic_load(&arr[threadIdx.x], __ATOMIC_ACQUIRE, __HIP_MEMORY_SCOPE_AGENT);
        __syncthreads();
        if (threadIdx.x == 0)
            __hip_atomic_store(&go[phase], 1, __ATOMIC_RELEASE, __HIP_MEMORY_SCOPE_AGENT);
    }
    if (threadIdx.x == 0) {
        while (__hip_atomic_load(&go[phase], __ATOMIC_RELAXED, __HIP_MEMORY_SCOPE_AGENT) == 0)
            __builtin_amdgcn_s_sleep(8);
        (void)__hip_atomic_load(&go[phase], __ATOMIC_ACQUIRE, __HIP_MEMORY_SCOPE_AGENT);
    }
    __syncthreads();
}

__global__ __launch_bounds__(256) void fused(const float* __restrict__ he,
                                             const float* __restrict__ w0,
                                             const float* __restrict__ b0,
                                             const float* __restrict__ w1,
                                             int* __restrict__ arrive,
                                             int* __restrict__ go,
                                             float* __restrict__ Cpart,
                                             float* __restrict__ Ppart,
                                             float* __restrict__ Aw,
                                             float* __restrict__ outp) {
    __shared__ float smem[12864];  // 51456 B
    const int tid = threadIdx.x;
    const int bid = blockIdx.x;
    const int tx = tid & 15, ty = tid >> 4;

    // ---------------- Phase A: C-partials, NT GEMM, 128x128 tile, 8x8 micro, K-split 8
    // 1 B/MAC LDS -> ~3.4 us
    {
        const int ks = bid & 7, bi = (bid >> 3) & 3, bc = bid >> 5;
        const int c0 = bc * 128, i0 = bi * 128, kb0 = ks * 64;
        const int hrow0 = c0 & 511;
        const int dofs = (c0 >= 512) ? 512 : 0;
        float* As = smem;           // [d(32)][i(128)] stride AS_STR
        float* Bs = smem + 4224;    // [d(32)][c(128)] stride AS_STR
        v2f acc[8][4] = {};
        for (int kt = 0; kt < 2; ++kt) {
            const int kb = kb0 + kt * 32;
            #pragma unroll
            for (int r = 0; r < 4; ++r) {
                int f = tid + r * 256, row = f >> 3, kc = (f & 7) * 4;
                float4 a = *(const float4*)&he[(i0 + row) * 512 + kb + kc];
                As[(kc + 0) * AS_STR + row] = a.x;
                As[(kc + 1) * AS_STR + row] = a.y;
                As[(kc + 2) * AS_STR + row] = a.z;
                As[(kc + 3) * AS_STR + row] = a.w;
            }
            #pragma unroll
            for (int r = 0; r < 4; ++r) {
                int f = tid + r * 256, row = f >> 3, kc = (f & 7) * 4;
                float4 b = *(const float4*)&w0[(hrow0 + row) * 1024 + dofs + kb + kc];
                Bs[(kc + 0) * AS_STR + row] = b.x;
                Bs[(kc + 1) * AS_STR + row] = b.y;
                Bs[(kc + 2) * AS_STR + row] = b.z;
                Bs[(kc + 3) * AS_STR + row] = b.w;
            }
            __syncthreads();
            #pragma unroll
            for (int k = 0; k < 32; ++k) {
                float4 a0 = *(const float4*)&As[k * AS_STR + 4 * ty];
                float4 a1 = *(const float4*)&As[k * AS_STR + 64 + 4 * ty];
                float4 q0 = *(const float4*)&Bs[k * AS_STR + 4 * tx];
                float4 q1 = *(const float4*)&Bs[k * AS_STR + 64 + 4 * tx];
                v2f bb[4] = {{q0.x, q0.y}, {q0.z, q0.w}, {q1.x, q1.y}, {q1.z, q1.w}};
                float av[8] = {a0.x, a0.y, a0.z, a0.w, a1.x, a1.y, a1.z, a1.w};
                #pragma unroll
                for (int ii = 0; ii < 8; ++ii) {
                    v2f av2 = {av[ii], av[ii]};
                    #pragma unroll
                    for (int jj = 0; jj < 4; ++jj)
                        acc[ii][jj] = __builtin_elementwise_fma(av2, bb[jj], acc[ii][jj]);
                }
            }
            __syncthreads();
        }
        float* op = Cpart + (size_t)ks * 524288;
        #pragma unroll
        for (int ii = 0; ii < 8; ++ii) {
            int row = i0 + ((ii < 4) ? (4 * ty + ii) : (64 + 4 * ty + ii - 4));
            float4 v0 = make_float4(acc[ii][0].x, acc[ii][0].y, acc[ii][1].x, acc[ii][1].y);
            float4 v1 = make_float4(acc[ii][2].x, acc[ii][2].y, acc[ii][3].x, acc[ii][3].y);
            *(float4*)&op[row * 1024 + c0 + 4 * tx] = v0;
            *(float4*)&op[row * 1024 + c0 + 64 + 4 * tx] = v1;
        }
    }
    gbar(arrive, go, 0);

    // ---------------- Phase B: score partials, 128i x 64j tile, 8x4 micro, h-slice 64
    // 8 C-partials summed (+bias) during staging.
    {
        const int hs = bid & 7, bi = (bid >> 3) & 3, bj = bid >> 5;
        const int j0 = bj * 64, i0 = bi * 128, hb = hs * 64;
        float* As = smem;            // [h(64)][i(128)] stride AS_STR
        float* Bs = smem + 8448;     // [h(64)][j(64)]  stride BS_STR
        float* Ws = smem + 12800;
        #pragma unroll
        for (int r = 0; r < 8; ++r) {
            int f = tid + r * 256, row = f >> 4, hc = (f & 15) * 4;
            int g = (i0 + row) * 1024 + hb + hc;
            float4 s = *(const float4*)&Cpart[g];
            #pragma unroll
            for (int sl = 1; sl < 8; ++sl) {
                float4 a = *(const float4*)&Cpart[sl * 524288 + g];
                s.x += a.x; s.y += a.y; s.z += a.z; s.w += a.w;
            }
            As[(hc + 0) * AS_STR + row] = s.x;
            As[(hc + 1) * AS_STR + row] = s.y;
            As[(hc + 2) * AS_STR + row] = s.z;
            As[(hc + 3) * AS_STR + row] = s.w;
        }
        #pragma unroll
        for (int r = 0; r < 4; ++r) {
            int f = tid + r * 256, row = f >> 4, hc = (f & 15) * 4;
            int g = (j0 + row) * 1024 + 512 + hb + hc;
            float4 s = *(const float4*)&b0[hb + hc];
            #pragma unroll
            for (int sl = 0; sl < 8; ++sl) {
                float4 a = *(const float4*)&Cpart[sl * 524288 + g];
                s.x += a.x; s.y += a.y; s.z += a.z; s.w += a.w;
            }
            Bs[(hc + 0) * BS_STR + row] = s.x;
            Bs[(hc + 1) * BS_STR + row] = s.y;
            Bs[(hc + 2) * BS_STR + row] = s.z;
            Bs[(hc + 3) * BS_STR + row] = s.w;
        }
        if (tid < 64) Ws[tid] = w1[hb + tid];
        __syncthreads();
        v2f acc[8][2] = {};
        const v2f z2 = {0.0f, 0.0f};
        #pragma unroll 16
        for (int k = 0; k < 64; ++k) {
            float4 a0 = *(const float4*)&As[k * AS_STR + 4 * ty];
            float4 a1 = *(const float4*)&As[k * AS_STR + 64 + 4 * ty];
            float4 b = *(const float4*)&Bs[k * BS_STR + 4 * tx];
            float w = Ws[k];
            v2f w2 = {w, w};
            v2f b01 = {b.x, b.y}, b23 = {b.z, b.w};
            float av[8] = {a0.x, a0.y, a0.z, a0.w, a1.x, a1.y, a1.z, a1.w};
            #pragma unroll
            for (int ii = 0; ii < 8; ++ii) {
                v2f av2 = {av[ii], av[ii]};
                v2f x0 = av2 + b01;
                v2f x1 = av2 + b23;
                x0 = __builtin_elementwise_max(x0, z2);
                x1 = __builtin_elementwise_max(x1, z2);
                acc[ii][0] = __builtin_elementwise_fma(x0, w2, acc[ii][0]);
                acc[ii][1] = __builtin_elementwise_fma(x1, w2, acc[ii][1]);
            }
        }
        float* op = Ppart + (size_t)hs * 262144;
        #pragma unroll
        for (int ii = 0; ii < 8; ++ii) {
            int row = i0 + ((ii < 4) ? (4 * ty + ii) : (64 + 4 * ty + ii - 4));
            float4 v = make_float4(acc[ii][0].x, acc[ii][0].y, acc[ii][1].x, acc[ii][1].y);
            *(float4*)&op[row * 512 + j0 + 4 * tx] = v;
        }
    }
    gbar(arrive, go, 1);

    // ---------------- Phase C: reduce 8 P-partials + row softmax (2 rows/block)
    {
        float* red = smem;
        for (int rr = 0; rr < 2; ++rr) {
            const int i = bid * 2 + rr;
            float p0 = 0.f, p1 = 0.f;
            #pragma unroll
            for (int s = 0; s < 8; ++s) {
                p0 += Ppart[s * 262144 + i * 512 + tid];
                p1 += Ppart[s * 262144 + i * 512 + tid + 256];
            }
            red[tid] = fmaxf(p0, p1);
            __syncthreads();
            for (int s = 128; s > 0; s >>= 1) {
                if (tid < s) red[tid] = fmaxf(red[tid], red[tid + s]);
                __syncthreads();
            }
            const float m = red[0];
            __syncthreads();
            const float e0 = __expf(p0 - m);
            const float e1 = __expf(p1 - m);
            red[tid] = e0 + e1;
            __syncthreads();
            for (int s = 128; s > 0; s >>= 1) {
                if (tid < s) red[tid] += red[tid + s];
                __syncthreads();
            }
            const float inv = 1.0f / red[0];
            Aw[i * 512 + tid] = e0 * inv;
            Aw[i * 512 + tid + 256] = e1 * inv;
            __syncthreads();
        }
    }
    gbar(arrive, go, 2);

    // ---------------- Phase D: out = Aw @ he, 32x32 tile, BK=32, 2x2 micro
    {
        const int d0 = (bid & 15) * 32;
        const int i0 = (bid >> 4) * 32;
        float* As = smem;            // [k(32)][i(32)] stride 34
        float* Bs = smem + 1088;     // [k(32)][d(32)] stride 36
        v2f acc[2] = {};
        for (int kt = 0; kt < 16; ++kt) {
            const int kb = kt * 32;
            {
                int row = tid >> 3, kc = (tid & 7) * 4;
                float4 a = *(const float4*)&Aw[(i0 + row) * 512 + kb + kc];
                As[(kc + 0) * 34 + row] = a.x;
                As[(kc + 1) * 34 + row] = a.y;
                As[(kc + 2) * 34 + row] = a.z;
                As[(kc + 3) * 34 + row] = a.w;
            }
            {
                int row = tid >> 3, dc = (tid & 7) * 4;
                *(float4*)&Bs[row * 36 + dc] = *(const float4*)&he[(kb + row) * 512 + d0 + dc];
            }
            __syncthreads();
            #pragma unroll
            for (int k = 0; k < 32; ++k) {
                float2 a = *(const float2*)&As[k * 34 + 2 * ty];
                float2 b = *(const float2*)&Bs[k * 36 + 2 * tx];
                v2f b2 = {b.x, b.y};
                v2f a0 = {a.x, a.x}, a1 = {a.y, a.y};
                acc[0] = __builtin_elementwise_fma(a0, b2, acc[0]);
                acc[1] = __builtin_elementwise_fma(a1, b2, acc[1]);
            }
            __syncthreads();
        }
        #pragma unroll
        for (int ii = 0; ii < 2; ++ii) {
            float2 v = make_float2(acc[ii].x, acc[ii].y);
            *(float2*)&outp[(i0 + 2 * ty + ii) * 512 + d0 + 2 * tx] = v;
        }
    }
}

extern "C" void kernel_launch(void* const* d_in, const int* in_sizes, int n_in,
                              void* d_out, int out_size, void* d_ws, size_t ws_size,
                              hipStream_t stream) {
    const float* he = (const float*)d_in[0];   // (512, 512)
    const float* w0 = (const float*)d_in[1];   // (512, 1024)
    const float* b0 = (const float*)d_in[2];   // (512,)
    const float* w1 = (const float*)d_in[3];   // (1, 512)
    // d_in[4] = W1_b: softmax-invariant, unused.
    int* arrive = (int*)d_ws;                  // [3][256]
    int* go = arrive + 3 * NBLK;               // [3]
    float* base = (float*)((char*)d_ws + 4096);
    float* Cpart = base;                       // 8*512*1024
    float* Ppart = Cpart + 8 * 524288;         // 8*512*512
    float* Aw    = Ppart + 8 * 262144;         // 512*512

    hipMemsetAsync(d_ws, 0, 4096, stream);     // zero barrier flags every call
    fused<<<NBLK, 256, 0, stream>>>(he, w0, b0, w1, arrive, go, Cpart, Ppart, Aw,
                                    (float*)d_out);
}

// Round 7
// 141.663 us; speedup vs baseline: 1.7814x; 1.0685x over previous
//
#include <hip/hip_runtime.h>

// N=512, D=512 fp32. Four kernels (in-kernel grid barriers proven 2x worse than
// CP inter-kernel sync on 8 non-coherent XCDs -- rounds 4-6).
// pre_i[i,h] = sum_d he[i,d]*W0[h,d]; pre_j[j,h] = sum_d he[j,d]*W0[h,512+d]
// p[i,j] = sum_h relu(pre_i + pre_j + b0[h]) * w1[h]   (W1_b softmax-invariant)
// out = softmax_rows(p) @ h_e
//
// ws: Cpart[8][512][1024] | Ppart[8][512][512] | Aw[512][512]

typedef float v2f __attribute__((ext_vector_type(2)));

#define AS_STR 132   // 128 + 4 pad
#define BS_STR 68    // 64 + 4 pad

// ---------------------------------------------------------------------------
// K1: C-partials, NT GEMM, 128x128 tile, 8x8 micro (1 B/MAC LDS), K-split 8.
// grid 256 blocks. (Validated as round-6 phase A.)
__global__ __launch_bounds__(256) void k_pre(const float* __restrict__ he,
                                             const float* __restrict__ w0,
                                             float* __restrict__ Cpart) {
    __shared__ float smem[8448];
    const int tid = threadIdx.x, bid = blockIdx.x;
    const int tx = tid & 15, ty = tid >> 4;
    const int ks = bid & 7, bi = (bid >> 3) & 3, bc = bid >> 5;
    const int c0 = bc * 128, i0 = bi * 128, kb0 = ks * 64;
    const int hrow0 = c0 & 511;
    const int dofs = (c0 >= 512) ? 512 : 0;
    float* As = smem;           // [d(32)][i(128)]
    float* Bs = smem + 4224;    // [d(32)][c(128)]
    v2f acc[8][4] = {};
    for (int kt = 0; kt < 2; ++kt) {
        const int kb = kb0 + kt * 32;
        #pragma unroll
        for (int r = 0; r < 4; ++r) {
            int f = tid + r * 256, row = f >> 3, kc = (f & 7) * 4;
            float4 a = *(const float4*)&he[(i0 + row) * 512 + kb + kc];
            As[(kc + 0) * AS_STR + row] = a.x;
            As[(kc + 1) * AS_STR + row] = a.y;
            As[(kc + 2) * AS_STR + row] = a.z;
            As[(kc + 3) * AS_STR + row] = a.w;
        }
        #pragma unroll
        for (int r = 0; r < 4; ++r) {
            int f = tid + r * 256, row = f >> 3, kc = (f & 7) * 4;
            float4 b = *(const float4*)&w0[(hrow0 + row) * 1024 + dofs + kb + kc];
            Bs[(kc + 0) * AS_STR + row] = b.x;
            Bs[(kc + 1) * AS_STR + row] = b.y;
            Bs[(kc + 2) * AS_STR + row] = b.z;
            Bs[(kc + 3) * AS_STR + row] = b.w;
        }
        __syncthreads();
        #pragma unroll
        for (int k = 0; k < 32; ++k) {
            float4 a0 = *(const float4*)&As[k * AS_STR + 4 * ty];
            float4 a1 = *(const float4*)&As[k * AS_STR + 64 + 4 * ty];
            float4 q0 = *(const float4*)&Bs[k * AS_STR + 4 * tx];
            float4 q1 = *(const float4*)&Bs[k * AS_STR + 64 + 4 * tx];
            v2f bb[4] = {{q0.x, q0.y}, {q0.z, q0.w}, {q1.x, q1.y}, {q1.z, q1.w}};
            float av[8] = {a0.x, a0.y, a0.z, a0.w, a1.x, a1.y, a1.z, a1.w};
            #pragma unroll
            for (int ii = 0; ii < 8; ++ii) {
                v2f av2 = {av[ii], av[ii]};
                #pragma unroll
                for (int jj = 0; jj < 4; ++jj)
                    acc[ii][jj] = __builtin_elementwise_fma(av2, bb[jj], acc[ii][jj]);
            }
        }
        __syncthreads();
    }
    float* op = Cpart + (size_t)ks * 524288;
    #pragma unroll
    for (int ii = 0; ii < 8; ++ii) {
        int row = i0 + ((ii < 4) ? (4 * ty + ii) : (64 + 4 * ty + ii - 4));
        float4 v0 = make_float4(acc[ii][0].x, acc[ii][0].y, acc[ii][1].x, acc[ii][1].y);
        float4 v1 = make_float4(acc[ii][2].x, acc[ii][2].y, acc[ii][3].x, acc[ii][3].y);
        *(float4*)&op[row * 1024 + c0 + 4 * tx] = v0;
        *(float4*)&op[row * 1024 + c0 + 64 + 4 * tx] = v1;
    }
}

// ---------------------------------------------------------------------------
// K2: score partials, 128i x 64j tile, 8x4 micro, h-slice 64; 8 C-partials
// summed (+bias) during staging. grid 256 blocks. (Validated as round-6 phase B.)
__global__ __launch_bounds__(256) void k_score(const float* __restrict__ Cpart,
                                               const float* __restrict__ b0,
                                               const float* __restrict__ w1,
                                               float* __restrict__ Ppart) {
    __shared__ float smem[12864];
    const int tid = threadIdx.x, bid = blockIdx.x;
    const int tx = tid & 15, ty = tid >> 4;
    const int hs = bid & 7, bi = (bid >> 3) & 3, bj = bid >> 5;
    const int j0 = bj * 64, i0 = bi * 128, hb = hs * 64;
    float* As = smem;            // [h(64)][i(128)]
    float* Bs = smem + 8448;     // [h(64)][j(64)]
    float* Ws = smem + 12800;
    #pragma unroll
    for (int r = 0; r < 8; ++r) {
        int f = tid + r * 256, row = f >> 4, hc = (f & 15) * 4;
        int g = (i0 + row) * 1024 + hb + hc;
        float4 s = *(const float4*)&Cpart[g];
        #pragma unroll
        for (int sl = 1; sl < 8; ++sl) {
            float4 a = *(const float4*)&Cpart[sl * 524288 + g];
            s.x += a.x; s.y += a.y; s.z += a.z; s.w += a.w;
        }
        As[(hc + 0) * AS_STR + row] = s.x;
        As[(hc + 1) * AS_STR + row] = s.y;
        As[(hc + 2) * AS_STR + row] = s.z;
        As[(hc + 3) * AS_STR + row] = s.w;
    }
    #pragma unroll
    for (int r = 0; r < 4; ++r) {
        int f = tid + r * 256, row = f >> 4, hc = (f & 15) * 4;
        int g = (j0 + row) * 1024 + 512 + hb + hc;
        float4 s = *(const float4*)&b0[hb + hc];
        #pragma unroll
        for (int sl = 0; sl < 8; ++sl) {
            float4 a = *(const float4*)&Cpart[sl * 524288 + g];
            s.x += a.x; s.y += a.y; s.z += a.z; s.w += a.w;
        }
        Bs[(hc + 0) * BS_STR + row] = s.x;
        Bs[(hc + 1) * BS_STR + row] = s.y;
        Bs[(hc + 2) * BS_STR + row] = s.z;
        Bs[(hc + 3) * BS_STR + row] = s.w;
    }
    if (tid < 64) Ws[tid] = w1[hb + tid];
    __syncthreads();
    v2f acc[8][2] = {};
    const v2f z2 = {0.0f, 0.0f};
    #pragma unroll 16
    for (int k = 0; k < 64; ++k) {
        float4 a0 = *(const float4*)&As[k * AS_STR + 4 * ty];
        float4 a1 = *(const float4*)&As[k * AS_STR + 64 + 4 * ty];
        float4 b = *(const float4*)&Bs[k * BS_STR + 4 * tx];
        float w = Ws[k];
        v2f w2 = {w, w};
        v2f b01 = {b.x, b.y}, b23 = {b.z, b.w};
        float av[8] = {a0.x, a0.y, a0.z, a0.w, a1.x, a1.y, a1.z, a1.w};
        #pragma unroll
        for (int ii = 0; ii < 8; ++ii) {
            v2f av2 = {av[ii], av[ii]};
            v2f x0 = av2 + b01;
            v2f x1 = av2 + b23;
            x0 = __builtin_elementwise_max(x0, z2);
            x1 = __builtin_elementwise_max(x1, z2);
            acc[ii][0] = __builtin_elementwise_fma(x0, w2, acc[ii][0]);
            acc[ii][1] = __builtin_elementwise_fma(x1, w2, acc[ii][1]);
        }
    }
    float* op = Ppart + (size_t)hs * 262144;
    #pragma unroll
    for (int ii = 0; ii < 8; ++ii) {
        int row = i0 + ((ii < 4) ? (4 * ty + ii) : (64 + 4 * ty + ii - 4));
        float4 v = make_float4(acc[ii][0].x, acc[ii][0].y, acc[ii][1].x, acc[ii][1].y);
        *(float4*)&op[row * 512 + j0 + 4 * tx] = v;
    }
}

// ---------------------------------------------------------------------------
// K3: reduce 8 P-partials, row softmax -> Aw. grid 512 blocks.
__global__ __launch_bounds__(256) void k_softmax(const float* __restrict__ Ppart,
                                                 float* __restrict__ Aw) {
    const int i = blockIdx.x;
    const int tid = threadIdx.x;
    float p0 = 0.f, p1 = 0.f;
    #pragma unroll
    for (int s = 0; s < 8; ++s) {
        p0 += Ppart[s * 262144 + i * 512 + tid];
        p1 += Ppart[s * 262144 + i * 512 + tid + 256];
    }
    __shared__ float red[256];
    red[tid] = fmaxf(p0, p1);
    __syncthreads();
    for (int s = 128; s > 0; s >>= 1) {
        if (tid < s) red[tid] = fmaxf(red[tid], red[tid + s]);
        __syncthreads();
    }
    const float m = red[0];
    __syncthreads();
    const float e0 = __expf(p0 - m);
    const float e1 = __expf(p1 - m);
    red[tid] = e0 + e1;
    __syncthreads();
    for (int s = 128; s > 0; s >>= 1) {
        if (tid < s) red[tid] += red[tid + s];
        __syncthreads();
    }
    const float inv = 1.0f / red[0];
    Aw[i * 512 + tid] = e0 * inv;
    Aw[i * 512 + tid + 256] = e1 * inv;
}

// ---------------------------------------------------------------------------
// K4: out += Aw @ he, split-K(j) 8 via atomicAdd into zeroed d_out.
// grid (8 d-tiles of 64, 4 i-tiles of 128, 8 j-slices of 64), 8x4 micro.
__global__ __launch_bounds__(256) void k_out(const float* __restrict__ Aw,
                                             const float* __restrict__ he,
                                             float* __restrict__ outp) {
    __shared__ float smem[12800];
    const int tid = threadIdx.x;
    const int tx = tid & 15, ty = tid >> 4;
    const int d0 = blockIdx.x * 64;
    const int i0 = blockIdx.y * 128;
    const int jb = blockIdx.z * 64;
    float* As = smem;            // [j(64)][i(128)] transposed
    float* Bs = smem + 8448;     // [j(64)][d(64)]  natural
    #pragma unroll
    for (int r = 0; r < 8; ++r) {
        int f = tid + r * 256, row = f >> 4, jc = (f & 15) * 4;
        float4 a = *(const float4*)&Aw[(i0 + row) * 512 + jb + jc];
        As[(jc + 0) * AS_STR + row] = a.x;
        As[(jc + 1) * AS_STR + row] = a.y;
        As[(jc + 2) * AS_STR + row] = a.z;
        As[(jc + 3) * AS_STR + row] = a.w;
    }
    #pragma unroll
    for (int r = 0; r < 4; ++r) {
        int f = tid + r * 256, row = f >> 4, dc = (f & 15) * 4;
        *(float4*)&Bs[row * BS_STR + dc] = *(const float4*)&he[(jb + row) * 512 + d0 + dc];
    }
    __syncthreads();
    v2f acc[8][2] = {};
    #pragma unroll 16
    for (int k = 0; k < 64; ++k) {
        float4 a0 = *(const float4*)&As[k * AS_STR + 4 * ty];
        float4 a1 = *(const float4*)&As[k * AS_STR + 64 + 4 * ty];
        float4 b = *(const float4*)&Bs[k * BS_STR + 4 * tx];
        v2f b01 = {b.x, b.y}, b23 = {b.z, b.w};
        float av[8] = {a0.x, a0.y, a0.z, a0.w, a1.x, a1.y, a1.z, a1.w};
        #pragma unroll
        for (int ii = 0; ii < 8; ++ii) {
            v2f av2 = {av[ii], av[ii]};
            acc[ii][0] = __builtin_elementwise_fma(av2, b01, acc[ii][0]);
            acc[ii][1] = __builtin_elementwise_fma(av2, b23, acc[ii][1]);
        }
    }
    #pragma unroll
    for (int ii = 0; ii < 8; ++ii) {
        int row = i0 + ((ii < 4) ? (4 * ty + ii) : (64 + 4 * ty + ii - 4));
        float* dst = &outp[row * 512 + d0 + 4 * tx];
        atomicAdd(dst + 0, acc[ii][0].x);
        atomicAdd(dst + 1, acc[ii][0].y);
        atomicAdd(dst + 2, acc[ii][1].x);
        atomicAdd(dst + 3, acc[ii][1].y);
    }
}

extern "C" void kernel_launch(void* const* d_in, const int* in_sizes, int n_in,
                              void* d_out, int out_size, void* d_ws, size_t ws_size,
                              hipStream_t stream) {
    const float* he = (const float*)d_in[0];   // (512, 512)
    const float* w0 = (const float*)d_in[1];   // (512, 1024)
    const float* b0 = (const float*)d_in[2];   // (512,)
    const float* w1 = (const float*)d_in[3];   // (1, 512)
    // d_in[4] = W1_b: softmax-invariant, unused.
    float* Cpart = (float*)d_ws;               // 8*512*1024
    float* Ppart = Cpart + 8 * 524288;         // 8*512*512
    float* Aw    = Ppart + 8 * 262144;         // 512*512

    hipMemsetAsync(d_out, 0, (size_t)out_size * sizeof(float), stream);
    k_pre    <<<dim3(256),     256, 0, stream>>>(he, w0, Cpart);
    k_score  <<<dim3(256),     256, 0, stream>>>(Cpart, b0, w1, Ppart);
    k_softmax<<<dim3(512),     256, 0, stream>>>(Ppart, Aw);
    k_out    <<<dim3(8, 4, 8), 256, 0, stream>>>(Aw, he, (float*)d_out);
}